// Round 1
// baseline (2064.466 us; speedup 1.0000x reference)
//
#include <hip/hip_runtime.h>

#define C_   64
#define HH   224
#define WW   224
#define TS   16
#define TSH  18                 // TS + 2 halo
#define NPIX (TSH * TSH)        // 324

__global__ __launch_bounds__(256, 1) void dynconv_fused_f32(
    const float* __restrict__ x, const float* __restrict__ w1,
    const float* __restrict__ w2, float* __restrict__ out)
{
    __shared__ float xs[C_ * NPIX];   // 82,944 B: x tile + halo, per channel
    __shared__ float hs[C_ * 256];    // 65,536 B: per-thread h[o] at hs[o*256+tid]

    const int b   = blockIdx.z;
    const int ty0 = blockIdx.y * TS;
    const int tx0 = blockIdx.x * TS;
    const int tid = threadIdx.x;
    const int HW  = HH * WW;

    const float* xb = x + (size_t)b * C_ * HW;

    // ---- stage x tile (+1 halo, zero-padded) into LDS ----
    for (int i = tid; i < C_ * NPIX; i += 256) {
        int c   = i / NPIX;
        int rem = i - c * NPIX;
        int r   = rem / TSH;
        int col = rem - r * TSH;
        int gy  = ty0 + r - 1;
        int gx  = tx0 + col - 1;
        float v = 0.f;
        if ((unsigned)gy < (unsigned)HH && (unsigned)gx < (unsigned)WW)
            v = xb[c * HW + gy * WW + gx];
        xs[i] = v;
    }
    __syncthreads();

    const int ty  = tid >> 4, tx = tid & 15;
    const int pid = (ty + 1) * TSH + (tx + 1);

    // ---- phase 1: h[o] = relu(sum_c w1[o,c] * x[c]) ----
    float xv[C_];
    #pragma unroll
    for (int c = 0; c < C_; ++c) xv[c] = xs[c * NPIX + pid];

    for (int o = 0; o < C_; o += 4) {
        const float* w1r = w1 + o * C_;   // wave-uniform -> scalar loads
        float a0 = 0.f, a1 = 0.f, a2 = 0.f, a3 = 0.f;
        #pragma unroll
        for (int c = 0; c < C_; ++c) {
            float xc = xv[c];
            a0 = fmaf(w1r[c],          xc, a0);
            a1 = fmaf(w1r[C_ + c],     xc, a1);
            a2 = fmaf(w1r[2 * C_ + c], xc, a2);
            a3 = fmaf(w1r[3 * C_ + c], xc, a3);
        }
        hs[(o + 0) * 256 + tid] = fmaxf(a0, 0.f);
        hs[(o + 1) * 256 + tid] = fmaxf(a1, 0.f);
        hs[(o + 2) * 256 + tid] = fmaxf(a2, 0.f);
        hs[(o + 3) * 256 + tid] = fmaxf(a3, 0.f);
    }
    // no barrier needed: each thread reads only its own hs column

    // ---- phase 2: per channel, kern[9] = w2[c*9+k,:] . h ; out = kern . patch ----
    const int gy = ty0 + ty, gx = tx0 + tx;
    float* ob = out + (size_t)b * C_ * HW + gy * WW + gx;
    const int nbase = ty * TSH + tx;   // top-left of this pixel's 3x3 in xs plane

    for (int c = 0; c < C_; ++c) {
        const float* xc = &xs[c * NPIX + nbase];
        float xn0 = xc[0],         xn1 = xc[1],           xn2 = xc[2];
        float xn3 = xc[TSH],       xn4 = xc[TSH + 1],     xn5 = xc[TSH + 2];
        float xn6 = xc[2 * TSH],   xn7 = xc[2 * TSH + 1], xn8 = xc[2 * TSH + 2];

        const float* w2r = w2 + (size_t)(c * 9) * C_;  // wave-uniform
        float k0=0.f,k1=0.f,k2=0.f,k3=0.f,k4=0.f,k5=0.f,k6=0.f,k7=0.f,k8=0.f;
        #pragma unroll
        for (int o = 0; o < C_; ++o) {
            float hv = hs[o * 256 + tid];
            k0 = fmaf(w2r[o],           hv, k0);
            k1 = fmaf(w2r[C_ + o],      hv, k1);
            k2 = fmaf(w2r[2 * C_ + o],  hv, k2);
            k3 = fmaf(w2r[3 * C_ + o],  hv, k3);
            k4 = fmaf(w2r[4 * C_ + o],  hv, k4);
            k5 = fmaf(w2r[5 * C_ + o],  hv, k5);
            k6 = fmaf(w2r[6 * C_ + o],  hv, k6);
            k7 = fmaf(w2r[7 * C_ + o],  hv, k7);
            k8 = fmaf(w2r[8 * C_ + o],  hv, k8);
        }
        float r = k0 * xn0 + k1 * xn1 + k2 * xn2
                + k3 * xn3 + k4 * xn4 + k5 * xn5
                + k6 * xn6 + k7 * xn7 + k8 * xn8;
        ob[(size_t)c * HW] = r;
    }
}

extern "C" void kernel_launch(void* const* d_in, const int* in_sizes, int n_in,
                              void* d_out, int out_size, void* d_ws, size_t ws_size,
                              hipStream_t stream) {
    const float* x  = (const float*)d_in[0];
    const float* w1 = (const float*)d_in[1];
    const float* w2 = (const float*)d_in[2];
    float* out = (float*)d_out;

    dim3 grid(WW / TS, HH / TS, 4);   // 14 x 14 x 4 = 784 blocks
    dynconv_fused_f32<<<grid, 256, 0, stream>>>(x, w1, w2, out);
}

// Round 2
// 308.825 us; speedup vs baseline: 6.6849x; 6.6849x over previous
//
#include <hip/hip_runtime.h>

#define HH   224
#define WW   224
#define HW_  (HH * WW)
#define TS   16
#define TSH  18
#define NPIX (TSH * TSH)   // 324
#define XSR  328           // padded xs row length in elements (656 B)

typedef __attribute__((ext_vector_type(8))) short bf16x8;
typedef __attribute__((ext_vector_type(4))) float f32x4;

static __device__ __forceinline__ unsigned short f2bf(float f) {
    unsigned u = __float_as_uint(f);
    u += 0x7FFFu + ((u >> 16) & 1u);          // RNE
    return (unsigned short)(u >> 16);
}
static __device__ __forceinline__ float bf2f(unsigned short h) {
    return __uint_as_float(((unsigned)h) << 16);
}

// LDS map (bytes): xs 64*656=41984 | w2s 576*128=73728 | hs 256*128=32768  => 148480
__global__ __launch_bounds__(256, 1) void dynconv_mfma(
    const float* __restrict__ x, const float* __restrict__ w1,
    const float* __restrict__ w2, float* __restrict__ out)
{
    __shared__ __align__(16) unsigned char lds[148480];
    unsigned short* xs  = (unsigned short*)lds;          // [c][XSR] bf16
    unsigned char*  w2s = lds + 41984;                   // 576 rows x 128B, XOR swz
    unsigned char*  hsb = lds + 41984 + 73728;           // 256 pix x 128B, XOR swz

    const int b    = blockIdx.z;
    const int ty0  = blockIdx.y * TS;
    const int tx0  = blockIdx.x * TS;
    const int tid  = threadIdx.x;
    const int lane = tid & 63;
    const int w    = tid >> 6;      // wave 0..3 -> tile rows w*4..w*4+3
    const int tx   = lane & 15;
    const int g    = lane >> 4;

    const float* xb = x + (size_t)b * 64 * HW_;

    // ---- stage x tile (fp32 -> bf16), channel-major [c][pix], pairs ----
    for (int i = tid; i < 64 * (NPIX / 2); i += 256) {
        int c  = i / 162;
        int pr = i - c * 162;
        int r  = pr / 9;
        int cp = pr - r * 9;
        int col0 = cp * 2;
        int gy  = ty0 + r - 1;
        int gx0 = tx0 + col0 - 1;
        float f0 = 0.f, f1 = 0.f;
        if ((unsigned)gy < (unsigned)HH) {
            const float* rowp = xb + c * HW_ + gy * WW;
            if ((unsigned)gx0 < (unsigned)WW)       f0 = rowp[gx0];
            if ((unsigned)(gx0 + 1) < (unsigned)WW) f1 = rowp[gx0 + 1];
        }
        unsigned pack = (unsigned)f2bf(f0) | ((unsigned)f2bf(f1) << 16);
        int p0 = r * TSH + col0;
        *(unsigned*)((unsigned char*)xs + c * 656 + p0 * 2) = pack;
    }

    // ---- stage w2 (fp32 -> bf16), 576 rows x 64 o, XOR-bit4 swizzle by row&7 ----
    {
        const float2* w2v = (const float2*)w2;
        for (int i = tid; i < 576 * 32; i += 256) {
            int row = i >> 5;
            int od  = i & 31;
            float2 f = w2v[i];
            unsigned pack = (unsigned)f2bf(f.x) | ((unsigned)f2bf(f.y) << 16);
            unsigned byte = ((unsigned)(row * 128 + od * 4)) ^ (unsigned)((row & 7) << 4);
            *(unsigned*)(w2s + byte) = pack;
        }
    }
    __syncthreads();

    // ---- GEMM1: h[o,pix] = relu(w1 . x), MFMA 16x16x32, A=w1 from global ----
    {
        bf16x8 aw1[4][2];
        #pragma unroll
        for (int mt = 0; mt < 4; ++mt) {
            #pragma unroll
            for (int kt = 0; kt < 2; ++kt) {
                const float* p = w1 + (mt * 16 + tx) * 64 + kt * 32 + g * 8;
                float4 fa = *(const float4*)p;
                float4 fb = *(const float4*)(p + 4);
                bf16x8 t;
                t[0] = (short)f2bf(fa.x); t[1] = (short)f2bf(fa.y);
                t[2] = (short)f2bf(fa.z); t[3] = (short)f2bf(fa.w);
                t[4] = (short)f2bf(fb.x); t[5] = (short)f2bf(fb.y);
                t[6] = (short)f2bf(fb.z); t[7] = (short)f2bf(fb.w);
                aw1[mt][kt] = t;
            }
        }
        #pragma unroll
        for (int q = 0; q < 4; ++q) {
            const int nt = w * 4 + q;
            const int center = (nt + 1) * TSH + tx + 1;
            bf16x8 bx[2];
            #pragma unroll
            for (int kt = 0; kt < 2; ++kt) {
                bf16x8 t;
                #pragma unroll
                for (int j = 0; j < 8; ++j)
                    t[j] = (short)xs[(kt * 32 + g * 8 + j) * XSR + center];
                bx[kt] = t;
            }
            const int pix = nt * 16 + tx;
            const unsigned swz = (unsigned)((tx & 7) << 4);
            #pragma unroll
            for (int mt = 0; mt < 4; ++mt) {
                f32x4 hc = {0.f, 0.f, 0.f, 0.f};
                hc = __builtin_amdgcn_mfma_f32_16x16x32_bf16(aw1[mt][0], bx[0], hc, 0, 0, 0);
                hc = __builtin_amdgcn_mfma_f32_16x16x32_bf16(aw1[mt][1], bx[1], hc, 0, 0, 0);
                unsigned lo = (unsigned)f2bf(fmaxf(hc[0], 0.f)) | ((unsigned)f2bf(fmaxf(hc[1], 0.f)) << 16);
                unsigned hi = (unsigned)f2bf(fmaxf(hc[2], 0.f)) | ((unsigned)f2bf(fmaxf(hc[3], 0.f)) << 16);
                unsigned byte = ((unsigned)(pix * 128 + mt * 32 + g * 8)) ^ swz;
                *(uint2*)(hsb + byte) = make_uint2(lo, hi);
            }
        }
    }

    // ---- preload GEMM2 B-fragments (h), own pixels only: no barrier needed ----
    bf16x8 bh0[2], bh1[2], bh2[2], bh3[2];
    {
        const unsigned swz = (unsigned)((tx & 7) << 4);
        #pragma unroll
        for (int kt = 0; kt < 2; ++kt) {
            unsigned p0 = (unsigned)(((w * 4 + 0) * 16 + tx) * 128 + kt * 64 + g * 16);
            unsigned p1 = (unsigned)(((w * 4 + 1) * 16 + tx) * 128 + kt * 64 + g * 16);
            unsigned p2 = (unsigned)(((w * 4 + 2) * 16 + tx) * 128 + kt * 64 + g * 16);
            unsigned p3 = (unsigned)(((w * 4 + 3) * 16 + tx) * 128 + kt * 64 + g * 16);
            bh0[kt] = *(const bf16x8*)(hsb + (p0 ^ swz));
            bh1[kt] = *(const bf16x8*)(hsb + (p1 ^ swz));
            bh2[kt] = *(const bf16x8*)(hsb + (p2 ^ swz));
            bh3[kt] = *(const bf16x8*)(hsb + (p3 ^ swz));
        }
    }

    // ---- precompute patch offsets per (q, r): tap k = g*4+r ----
    int poff[4][4];
    #pragma unroll
    for (int q = 0; q < 4; ++q) {
        #pragma unroll
        for (int r = 0; r < 4; ++r) {
            int kk = g * 4 + r;
            int kv = kk < 9 ? kk : 0;   // k>=9: kern==0 (zero-padded w2 rows), value irrelevant
            int dy = kv / 3;
            int dx = kv - dy * 3;
            poff[q][r] = (w * 4 + q + dy) * TSH + (tx + dx);
        }
    }

    float* outp = out + (size_t)b * 64 * HW_ + (size_t)(ty0 + w * 4 + g) * WW + tx0 + tx;

    // ---- GEMM2 + tap contract, per output channel c ----
    #pragma unroll 2
    for (int c = 0; c < 64; ++c) {
        bf16x8 a0, a1;
        if (tx < 9) {      // A rows = taps (padded 16); tx>=9 -> zero rows
            const int row = c * 9 + tx;
            const unsigned sw   = (unsigned)((row & 7) << 4);
            const unsigned base = (unsigned)(row * 128 + g * 16);
            a0 = *(const bf16x8*)(w2s + (base ^ sw));
            a1 = *(const bf16x8*)(w2s + ((base + 64) ^ sw));
        } else {
            a0 = bf16x8{0, 0, 0, 0, 0, 0, 0, 0};
            a1 = bf16x8{0, 0, 0, 0, 0, 0, 0, 0};
        }
        f32x4 acc0 = {0.f, 0.f, 0.f, 0.f};
        f32x4 acc1 = {0.f, 0.f, 0.f, 0.f};
        f32x4 acc2 = {0.f, 0.f, 0.f, 0.f};
        f32x4 acc3 = {0.f, 0.f, 0.f, 0.f};
        acc0 = __builtin_amdgcn_mfma_f32_16x16x32_bf16(a0, bh0[0], acc0, 0, 0, 0);
        acc1 = __builtin_amdgcn_mfma_f32_16x16x32_bf16(a0, bh1[0], acc1, 0, 0, 0);
        acc2 = __builtin_amdgcn_mfma_f32_16x16x32_bf16(a0, bh2[0], acc2, 0, 0, 0);
        acc3 = __builtin_amdgcn_mfma_f32_16x16x32_bf16(a0, bh3[0], acc3, 0, 0, 0);
        acc0 = __builtin_amdgcn_mfma_f32_16x16x32_bf16(a1, bh0[1], acc0, 0, 0, 0);
        acc1 = __builtin_amdgcn_mfma_f32_16x16x32_bf16(a1, bh1[1], acc1, 0, 0, 0);
        acc2 = __builtin_amdgcn_mfma_f32_16x16x32_bf16(a1, bh2[1], acc2, 0, 0, 0);
        acc3 = __builtin_amdgcn_mfma_f32_16x16x32_bf16(a1, bh3[1], acc3, 0, 0, 0);

        const unsigned short* xc = xs + c * XSR;
        float part0 = 0.f, part1 = 0.f, part2 = 0.f, part3 = 0.f;
        #pragma unroll
        for (int r = 0; r < 4; ++r) {
            part0 = fmaf(acc0[r], bf2f(xc[poff[0][r]]), part0);
            part1 = fmaf(acc1[r], bf2f(xc[poff[1][r]]), part1);
            part2 = fmaf(acc2[r], bf2f(xc[poff[2][r]]), part2);
            part3 = fmaf(acc3[r], bf2f(xc[poff[3][r]]), part3);
        }
        part0 += __shfl_xor(part0, 16, 64); part0 += __shfl_xor(part0, 32, 64);
        part1 += __shfl_xor(part1, 16, 64); part1 += __shfl_xor(part1, 32, 64);
        part2 += __shfl_xor(part2, 16, 64); part2 += __shfl_xor(part2, 32, 64);
        part3 += __shfl_xor(part3, 16, 64); part3 += __shfl_xor(part3, 32, 64);

        float v = part0;
        v = (g == 1) ? part1 : v;
        v = (g == 2) ? part2 : v;
        v = (g == 3) ? part3 : v;
        outp[(size_t)c * HW_] = v;   // 64 lanes = 4 rows x 64B, fully coalesced
    }
}

extern "C" void kernel_launch(void* const* d_in, const int* in_sizes, int n_in,
                              void* d_out, int out_size, void* d_ws, size_t ws_size,
                              hipStream_t stream) {
    (void)in_sizes; (void)n_in; (void)out_size; (void)d_ws; (void)ws_size;
    const float* x  = (const float*)d_in[0];
    const float* w1 = (const float*)d_in[1];
    const float* w2 = (const float*)d_in[2];
    float* out = (float*)d_out;

    dim3 grid(WW / TS, HH / TS, 4);   // 14 x 14 x 4
    dynconv_mfma<<<grid, 256, 0, stream>>>(x, w1, w2, out);
}

// Round 5
// 213.884 us; speedup vs baseline: 9.6523x; 1.4439x over previous
//
#include <hip/hip_runtime.h>

#define HH   224
#define WW   224
#define HW_  (HH * WW)
#define TS   16
#define TSH  18
#define NPIX (TSH * TSH)   // 324
#define XSR  328           // padded xs row length in elements (656 B)

typedef __attribute__((ext_vector_type(8))) short bf16x8;
typedef __attribute__((ext_vector_type(4))) float f32x4;

static __device__ __forceinline__ unsigned short f2bf(float f) {
    unsigned u = __float_as_uint(f);
    u += 0x7FFFu + ((u >> 16) & 1u);          // RNE
    return (unsigned short)(u >> 16);
}
static __device__ __forceinline__ float bf2f(unsigned short h) {
    return __uint_as_float(((unsigned)h) << 16);
}

// ---- pre-kernel: w1 -> bf16 [64][64]; w2 -> bf16 padded [64 ch][16 rows][64 o],
//      rows 9..15 zeroed so GEMM2 A-fragment loads are branchless ----
__global__ __launch_bounds__(256) void prep_weights(
    const float* __restrict__ w1, const float* __restrict__ w2,
    unsigned short* __restrict__ wsb)
{
    const int i = blockIdx.x * 256 + threadIdx.x;   // 0..65535
    unsigned short* w1b = wsb;                      // 4096 bf16
    unsigned short* w2p = wsb + 4096;               // 65536 bf16
    if (i < 4096) w1b[i] = f2bf(w1[i]);
    const int c  = i >> 10;
    const int rr = (i >> 6) & 15;
    const int o  = i & 63;
    float v = (rr < 9) ? w2[(c * 9 + rr) * 64 + o] : 0.f;
    w2p[i] = f2bf(v);
}

// LDS map (bytes): xs 64*656=41984 | hs 256*128=32768  => 74752 (2 blocks/CU)
__global__ __launch_bounds__(256, 2) void dynconv_mfma(
    const float* __restrict__ x, const unsigned short* __restrict__ wsb,
    float* __restrict__ out)
{
    __shared__ __align__(16) unsigned char lds[74752];
    unsigned short* xs  = (unsigned short*)lds;      // [c][XSR] bf16
    unsigned char*  hsb = lds + 41984;               // 256 pix x 128B, XOR swz

    const unsigned char* w1b = (const unsigned char*)wsb;            // bf16 [64][64]
    const unsigned char* w2p = (const unsigned char*)(wsb + 4096);   // bf16 [64][16][64]

    const int b    = blockIdx.z;
    const int ty0  = blockIdx.y * TS;
    const int tx0  = blockIdx.x * TS;
    const int tid  = threadIdx.x;
    const int lane = tid & 63;
    const int w    = tid >> 6;      // wave 0..3 -> tile rows w*4..w*4+3
    const int tx   = lane & 15;
    const int g    = lane >> 4;

    const float* xb = x + (size_t)b * 64 * HW_;

    // ---- stage x tile (fp32 -> bf16), channel-major [c][pix], pairs ----
    for (int i = tid; i < 64 * (NPIX / 2); i += 256) {
        int c  = i / 162;
        int pr = i - c * 162;
        int r  = pr / 9;
        int cp = pr - r * 9;
        int col0 = cp * 2;
        int gy  = ty0 + r - 1;
        int gx0 = tx0 + col0 - 1;
        float f0 = 0.f, f1 = 0.f;
        if ((unsigned)gy < (unsigned)HH) {
            const float* rowp = xb + c * HW_ + gy * WW;
            if ((unsigned)gx0 < (unsigned)WW)       f0 = rowp[gx0];
            if ((unsigned)(gx0 + 1) < (unsigned)WW) f1 = rowp[gx0 + 1];
        }
        unsigned pack = (unsigned)f2bf(f0) | ((unsigned)f2bf(f1) << 16);
        int p0 = r * TSH + col0;
        *(unsigned*)((unsigned char*)xs + c * 656 + p0 * 2) = pack;
    }
    __syncthreads();

    // ---- GEMM1: h[o,pix] = relu(w1 . x), MFMA 16x16x32, A=w1 bf16 from global ----
    {
        bf16x8 aw1[4][2];
        #pragma unroll
        for (int mt = 0; mt < 4; ++mt) {
            #pragma unroll
            for (int kt = 0; kt < 2; ++kt)
                aw1[mt][kt] = *(const bf16x8*)(w1b + (mt * 16 + tx) * 128 + kt * 64 + g * 16);
        }
        #pragma unroll
        for (int q = 0; q < 4; ++q) {
            const int nt = w * 4 + q;
            const int center = (nt + 1) * TSH + tx + 1;
            bf16x8 bx[2];
            #pragma unroll
            for (int kt = 0; kt < 2; ++kt) {
                bf16x8 t;
                #pragma unroll
                for (int j = 0; j < 8; ++j)
                    t[j] = (short)xs[(kt * 32 + g * 8 + j) * XSR + center];
                bx[kt] = t;
            }
            const int pix = nt * 16 + tx;
            const unsigned swz = (unsigned)((tx & 7) << 4);
            #pragma unroll
            for (int mt = 0; mt < 4; ++mt) {
                f32x4 hc = {0.f, 0.f, 0.f, 0.f};
                hc = __builtin_amdgcn_mfma_f32_16x16x32_bf16(aw1[mt][0], bx[0], hc, 0, 0, 0);
                hc = __builtin_amdgcn_mfma_f32_16x16x32_bf16(aw1[mt][1], bx[1], hc, 0, 0, 0);
                unsigned lo = (unsigned)f2bf(fmaxf(hc[0], 0.f)) | ((unsigned)f2bf(fmaxf(hc[1], 0.f)) << 16);
                unsigned hi = (unsigned)f2bf(fmaxf(hc[2], 0.f)) | ((unsigned)f2bf(fmaxf(hc[3], 0.f)) << 16);
                unsigned byte = ((unsigned)(pix * 128 + mt * 32 + g * 8)) ^ swz;
                *(uint2*)(hsb + byte) = make_uint2(lo, hi);
            }
        }
    }

    // ---- preload GEMM2 B-fragments (h), own pixels only: no barrier needed ----
    bf16x8 bh0[2], bh1[2], bh2[2], bh3[2];
    {
        const unsigned swz = (unsigned)((tx & 7) << 4);
        #pragma unroll
        for (int kt = 0; kt < 2; ++kt) {
            unsigned p0 = (unsigned)(((w * 4 + 0) * 16 + tx) * 128 + kt * 64 + g * 16);
            unsigned p1 = (unsigned)(((w * 4 + 1) * 16 + tx) * 128 + kt * 64 + g * 16);
            unsigned p2 = (unsigned)(((w * 4 + 2) * 16 + tx) * 128 + kt * 64 + g * 16);
            unsigned p3 = (unsigned)(((w * 4 + 3) * 16 + tx) * 128 + kt * 64 + g * 16);
            bh0[kt] = *(const bf16x8*)(hsb + (p0 ^ swz));
            bh1[kt] = *(const bf16x8*)(hsb + (p1 ^ swz));
            bh2[kt] = *(const bf16x8*)(hsb + (p2 ^ swz));
            bh3[kt] = *(const bf16x8*)(hsb + (p3 ^ swz));
        }
    }

    // ---- precompute patch offsets per (q, r): tap k = g*4+r ----
    int poff[4][4];
    #pragma unroll
    for (int q = 0; q < 4; ++q) {
        #pragma unroll
        for (int r = 0; r < 4; ++r) {
            int kk = g * 4 + r;
            int kv = kk < 9 ? kk : 0;   // k>=9: kern==0 (zero-padded w2p rows)
            int dy = kv / 3;
            int dx = kv - dy * 3;
            poff[q][r] = (w * 4 + q + dy) * TSH + (tx + dx);
        }
    }

    float* outp = out + (size_t)b * 64 * HW_ + (size_t)(ty0 + w * 4 + g) * WW + tx0 + tx;

    // ---- GEMM2 + tap contract, per output channel c; w2 frags prefetched ----
    const unsigned char* w2base = w2p + tx * 128 + g * 16;   // + c*2048 (+64 for kt=1)
    bf16x8 na0 = *(const bf16x8*)(w2base);
    bf16x8 na1 = *(const bf16x8*)(w2base + 64);

    for (int c = 0; c < 64; ++c) {
        bf16x8 a0 = na0, a1 = na1;
        const int cn = (c < 63) ? c + 1 : 63;
        na0 = *(const bf16x8*)(w2base + cn * 2048);
        na1 = *(const bf16x8*)(w2base + cn * 2048 + 64);

        f32x4 acc0 = {0.f, 0.f, 0.f, 0.f};
        f32x4 acc1 = {0.f, 0.f, 0.f, 0.f};
        f32x4 acc2 = {0.f, 0.f, 0.f, 0.f};
        f32x4 acc3 = {0.f, 0.f, 0.f, 0.f};
        acc0 = __builtin_amdgcn_mfma_f32_16x16x32_bf16(a0, bh0[0], acc0, 0, 0, 0);
        acc1 = __builtin_amdgcn_mfma_f32_16x16x32_bf16(a0, bh1[0], acc1, 0, 0, 0);
        acc2 = __builtin_amdgcn_mfma_f32_16x16x32_bf16(a0, bh2[0], acc2, 0, 0, 0);
        acc3 = __builtin_amdgcn_mfma_f32_16x16x32_bf16(a0, bh3[0], acc3, 0, 0, 0);
        acc0 = __builtin_amdgcn_mfma_f32_16x16x32_bf16(a1, bh0[1], acc0, 0, 0, 0);
        acc1 = __builtin_amdgcn_mfma_f32_16x16x32_bf16(a1, bh1[1], acc1, 0, 0, 0);
        acc2 = __builtin_amdgcn_mfma_f32_16x16x32_bf16(a1, bh2[1], acc2, 0, 0, 0);
        acc3 = __builtin_amdgcn_mfma_f32_16x16x32_bf16(a1, bh3[1], acc3, 0, 0, 0);

        const unsigned short* xc = xs + c * XSR;
        float part0 = 0.f, part1 = 0.f, part2 = 0.f, part3 = 0.f;
        #pragma unroll
        for (int r = 0; r < 4; ++r) {
            part0 = fmaf(acc0[r], bf2f(xc[poff[0][r]]), part0);
            part1 = fmaf(acc1[r], bf2f(xc[poff[1][r]]), part1);
            part2 = fmaf(acc2[r], bf2f(xc[poff[2][r]]), part2);
            part3 = fmaf(acc3[r], bf2f(xc[poff[3][r]]), part3);
        }
        part0 += __shfl_xor(part0, 16, 64); part0 += __shfl_xor(part0, 32, 64);
        part1 += __shfl_xor(part1, 16, 64); part1 += __shfl_xor(part1, 32, 64);
        part2 += __shfl_xor(part2, 16, 64); part2 += __shfl_xor(part2, 32, 64);
        part3 += __shfl_xor(part3, 16, 64); part3 += __shfl_xor(part3, 32, 64);

        float v = part0;
        v = (g == 1) ? part1 : v;
        v = (g == 2) ? part2 : v;
        v = (g == 3) ? part3 : v;
        outp[(size_t)c * HW_] = v;   // 64 lanes = 4 rows x 64B, fully coalesced
    }
}

extern "C" void kernel_launch(void* const* d_in, const int* in_sizes, int n_in,
                              void* d_out, int out_size, void* d_ws, size_t ws_size,
                              hipStream_t stream) {
    (void)in_sizes; (void)n_in; (void)out_size; (void)ws_size;
    const float* x  = (const float*)d_in[0];
    const float* w1 = (const float*)d_in[1];
    const float* w2 = (const float*)d_in[2];
    float* out = (float*)d_out;
    unsigned short* wsb = (unsigned short*)d_ws;    // 139264 bytes used

    prep_weights<<<256, 256, 0, stream>>>(w1, w2, wsb);

    dim3 grid(WW / TS, HH / TS, 4);   // 14 x 14 x 4
    dynconv_mfma<<<grid, 256, 0, stream>>>(x, wsb, out);
}